// Round 2
// baseline (11009.367 us; speedup 1.0000x reference)
//
#include <hip/hip_runtime.h>
#include <hip/hip_bf16.h>
#include <math.h>

// ---- problem constants ----
constexpr int B_    = 4;
constexpr int C_    = 96;
constexpr int H_    = 256;
constexpr int W_    = 256;
constexpr int WS_   = 8;
constexpr int NH_   = 4;
constexpr int SHIFT_= 4;
constexpr int HD_   = 24;        // C/NH
constexpr int NT_   = 64;        // WS*WS tokens per window
constexpr int NWH_  = H_/WS_;    // 32
constexpr int NWW_  = W_/WS_;    // 32
constexpr int NWIN_ = NWH_*NWW_; // 1024
constexpr int MLPH_ = 4*C_;      // 384
constexpr float EPS_ = 1e-6f;
constexpr float SCALE_ = 0.20412414523193150f; // 24^-0.5

__device__ __forceinline__ float b2f(__hip_bfloat16 v) { return __bfloat162float(v); }
__device__ __forceinline__ __hip_bfloat16 f2b(float v) { return __float2bfloat16(v); }

// region label in the (unshifted-mask) frame — matches reference img_mask slices
__device__ __forceinline__ int region_label(int coord, int limit) {
    if (coord < limit - WS_)    return 0;
    if (coord < limit - SHIFT_) return 1;
    return 2;
}

// One block per window: LN1 + QKV + windowed attention + proj + residual.
// Writes h = xp + attn_out as f32 directly into out ([B,C,H,W] layout).
__global__ __launch_bounds__(256) void attn_kernel(
    const float* __restrict__ x,       // [B,C,H,W]
    const float* __restrict__ norm_w,  // [C]
    const float* __restrict__ norm_b,  // [C]
    const float* __restrict__ qkv_w,   // [3C,C]
    const float* __restrict__ qkv_b,   // [3C]
    const float* __restrict__ proj_w,  // [C,C]
    const float* __restrict__ proj_b,  // [C]
    const float* __restrict__ rpb,     // [(2WS-1)^2, NH]
    float* __restrict__ hbuf)          // [B,C,H,W]  (= d_out, holds h)
{
    __shared__ float s_xln[NT_][C_];            // 24 KB  LN'd tokens
    __shared__ float s_q[NT_][HD_];             // 6 KB   (scale folded in)
    __shared__ float s_k[NT_][HD_];             // 6 KB
    __shared__ float s_v[NT_][HD_];             // 6 KB
    __shared__ __hip_bfloat16 s_out[NT_][C_];   // 12 KB  attn output (pre-proj)

    const int blk = blockIdx.x;
    const int b   = blk / NWIN_;
    const int wid = blk % NWIN_;
    const int wh  = wid / NWW_;
    const int ww  = wid % NWW_;
    const int tid = threadIdx.x;

    // ---- Phase 1: gather (roll + window partition) + LayerNorm ----
    // 4 lanes per token, 24 channels per lane.
    {
        const int t  = tid >> 2;
        const int qa = tid & 3;
        const int i  = t / WS_, j = t % WS_;
        const int gh = (wh*WS_ + i + SHIFT_) % H_;
        const int gw = (ww*WS_ + j + SHIFT_) % W_;
        const float* xb = x + (size_t)b*C_*H_*W_ + (size_t)gh*W_ + gw;
        float mu = 0.f, ss = 0.f;
        float v[24];
        #pragma unroll
        for (int cc = 0; cc < 24; ++cc) {
            const int c = qa*24 + cc;
            v[cc] = xb[(size_t)c*H_*W_];
            mu += v[cc]; ss += v[cc]*v[cc];
        }
        mu += __shfl_xor(mu, 1); mu += __shfl_xor(mu, 2);
        ss += __shfl_xor(ss, 1); ss += __shfl_xor(ss, 2);
        mu *= (1.f/C_);
        float var  = ss*(1.f/C_) - mu*mu;
        float rstd = rsqrtf(var + EPS_);
        #pragma unroll
        for (int cc = 0; cc < 24; ++cc) {
            const int c = qa*24 + cc;
            s_xln[t][c] = (v[cc] - mu)*rstd*norm_w[c] + norm_b[c];
        }
    }
    __syncthreads();

    // ---- Phase 2: per-head QKV + attention ----
    for (int hd = 0; hd < NH_; ++hd) {
        // QKV for this head: 3*64*24 = 4608 outputs over 256 threads
        for (int idx = tid; idx < 3*NT_*HD_; idx += 256) {
            const int which = idx / (NT_*HD_);
            const int rem   = idx % (NT_*HD_);
            const int t     = rem / HD_;
            const int d     = rem % HD_;
            const int row   = which*C_ + hd*HD_ + d;
            const float* wr = qkv_w + (size_t)row*C_;
            float acc = qkv_b[row];
            #pragma unroll 8
            for (int c = 0; c < C_; ++c) acc += s_xln[t][c] * wr[c];
            if      (which == 0) s_q[t][d] = acc * SCALE_;
            else if (which == 1) s_k[t][d] = acc;
            else                 s_v[t][d] = acc;
        }
        __syncthreads();

        // attention: 4 lanes per query row, 16 keys each (scores in regs)
        {
            const int t  = tid >> 2;
            const int qa = tid & 3;
            const int ti = t / WS_, tj = t % WS_;
            const int lab_t = region_label(wh*WS_ + ti, H_)*3 + region_label(ww*WS_ + tj, W_);
            float p[16];
            float mx = -1e30f;
            #pragma unroll
            for (int mm = 0; mm < 16; ++mm) {
                const int m  = qa*16 + mm;
                const int mi = m / WS_, mj = m % WS_;
                float acc = 0.f;
                #pragma unroll
                for (int d = 0; d < HD_; ++d) acc += s_q[t][d]*s_k[m][d];
                const int ridx = (ti - mi + WS_ - 1)*(2*WS_ - 1) + (tj - mj + WS_ - 1);
                acc += rpb[ridx*NH_ + hd];
                const int lab_m = region_label(wh*WS_ + mi, H_)*3 + region_label(ww*WS_ + mj, W_);
                if (lab_m != lab_t) acc -= 100.f;
                p[mm] = acc;
                mx = fmaxf(mx, acc);
            }
            mx = fmaxf(mx, __shfl_xor(mx, 1));
            mx = fmaxf(mx, __shfl_xor(mx, 2));
            float sum = 0.f;
            #pragma unroll
            for (int mm = 0; mm < 16; ++mm) { p[mm] = __expf(p[mm] - mx); sum += p[mm]; }
            sum += __shfl_xor(sum, 1);
            sum += __shfl_xor(sum, 2);
            const float inv = 1.f/sum;
            #pragma unroll
            for (int d = 0; d < HD_; ++d) {
                float acc = 0.f;
                #pragma unroll
                for (int mm = 0; mm < 16; ++mm) acc += p[mm]*s_v[qa*16 + mm][d];
                acc += __shfl_xor(acc, 1);
                acc += __shfl_xor(acc, 2);
                if (qa == 0) s_out[t][hd*HD_ + d] = f2b(acc*inv);
            }
        }
        __syncthreads();
    }

    // ---- Phase 3: proj + residual, scatter back (window-reverse + unroll) ----
    // idx % NT_ = token so consecutive lanes hit consecutive gw (coalesced-ish)
    for (int idx = tid; idx < NT_*C_; idx += 256) {
        const int t = idx % NT_;
        const int o = idx / NT_;
        const float* pw = proj_w + (size_t)o*C_;
        float acc = proj_b[o];
        #pragma unroll 8
        for (int c = 0; c < C_; ++c) acc += b2f(s_out[t][c])*pw[c];
        const int i  = t / WS_, j = t % WS_;
        const int gh = (wh*WS_ + i + SHIFT_) % H_;
        const int gw = (ww*WS_ + j + SHIFT_) % W_;
        const size_t gidx = ((size_t)(b*C_ + o)*H_ + gh)*W_ + gw;
        hbuf[gidx] = x[gidx] + acc;
    }
}

// One thread per token: LN2 + fc1 + exact GELU + fc2 + residual, in-place on out.
__global__ __launch_bounds__(256, 1) void mlp_kernel(
    const float* __restrict__ n2w,   // [C]
    const float* __restrict__ n2b,   // [C]
    const float* __restrict__ fc1w,  // [MLPH,C]
    const float* __restrict__ fc1b,  // [MLPH]
    const float* __restrict__ fc2w,  // [C,MLPH]
    const float* __restrict__ fc2b,  // [C]
    float* __restrict__ out)         // [B,C,H,W], holds h on entry
{
    const int tok = blockIdx.x*blockDim.x + threadIdx.x;  // < B*H*W
    const int b  = tok / (H_*W_);
    const int r  = tok % (H_*W_);

    // h for this token: out[((b*C+c)*H*W) + r], stride H*W over c (lane-coalesced per c)
    float* hp = out + (size_t)b*C_*H_*W_ + r;

    float y[C_], hres[C_];
    float mu = 0.f, ss = 0.f;
    #pragma unroll
    for (int c = 0; c < C_; ++c) {
        float v = hp[(size_t)c*H_*W_];
        hres[c] = v; y[c] = v; mu += v; ss += v*v;
    }
    mu *= (1.f/C_);
    float var  = ss*(1.f/C_) - mu*mu;
    float rstd = rsqrtf(var + EPS_);
    #pragma unroll
    for (int c = 0; c < C_; ++c) y[c] = (y[c] - mu)*rstd*n2w[c] + n2b[c];

    float acc[C_];
    #pragma unroll
    for (int c = 0; c < C_; ++c) acc[c] = 0.f;

    // fc1 -> gelu -> fc2 accumulate (weights lane-uniform -> scalar broadcast)
    for (int u = 0; u < MLPH_; ++u) {
        const float* wr = fc1w + (size_t)u*C_;
        float t = fc1b[u];
        #pragma unroll
        for (int c = 0; c < C_; ++c) t += y[c]*wr[c];
        const float g = 0.5f*t*(1.f + erff(t*0.70710678118654752f));
        const float* w2 = fc2w + u;
        #pragma unroll
        for (int c = 0; c < C_; ++c) acc[c] += g*w2[(size_t)c*MLPH_];
    }

    // residual + store back in place
    #pragma unroll
    for (int c = 0; c < C_; ++c) {
        hp[(size_t)c*H_*W_] = hres[c] + acc[c] + fc2b[c];
    }
}

extern "C" void kernel_launch(void* const* d_in, const int* in_sizes, int n_in,
                              void* d_out, int out_size, void* d_ws, size_t ws_size,
                              hipStream_t stream) {
    const float* x      = (const float*)d_in[0];
    const float* norm_w = (const float*)d_in[1];
    const float* norm_b = (const float*)d_in[2];
    const float* qkv_w  = (const float*)d_in[3];
    const float* qkv_b  = (const float*)d_in[4];
    const float* proj_w = (const float*)d_in[5];
    const float* proj_b = (const float*)d_in[6];
    const float* rpb    = (const float*)d_in[7];
    const float* n2w    = (const float*)d_in[8];
    const float* n2b    = (const float*)d_in[9];
    const float* fc1w   = (const float*)d_in[10];
    const float* fc1b   = (const float*)d_in[11];
    const float* fc2w   = (const float*)d_in[12];
    const float* fc2b   = (const float*)d_in[13];

    float* outp = (float*)d_out;  // [B,C,H,W] f32; also holds intermediate h

    attn_kernel<<<B_*NWIN_, 256, 0, stream>>>(x, norm_w, norm_b, qkv_w, qkv_b,
                                              proj_w, proj_b, rpb, outp);
    mlp_kernel<<<(B_*H_*W_)/256, 256, 0, stream>>>(n2w, n2b, fc1w, fc1b,
                                                   fc2w, fc2b, outp);
}

// Round 3
// 679.394 us; speedup vs baseline: 16.2047x; 16.2047x over previous
//
#include <hip/hip_runtime.h>
#include <hip/hip_bf16.h>
#include <math.h>

// ---- problem constants ----
constexpr int B_    = 4;
constexpr int C_    = 96;
constexpr int H_    = 256;
constexpr int W_    = 256;
constexpr int WS_   = 8;
constexpr int NH_   = 4;
constexpr int SHIFT_= 4;
constexpr int HD_   = 24;
constexpr int NT_   = 64;
constexpr int NWW_  = 32;
constexpr int NWIN_ = 1024;
constexpr int MLPH_ = 384;
constexpr int HW_   = H_*W_;
constexpr float EPS_   = 1e-6f;
constexpr float SCALE_ = 0.20412414523193150f; // 24^-0.5

using bf16   = __bf16;
using bf16x8 = __attribute__((ext_vector_type(8))) __bf16;
using bf16x4 = __attribute__((ext_vector_type(4))) __bf16;
using f32x4  = __attribute__((ext_vector_type(4))) float;

__device__ __forceinline__ f32x4 mfma16(bf16x8 a, bf16x8 b, f32x4 c) {
    return __builtin_amdgcn_mfma_f32_16x16x32_bf16(a, b, c, 0, 0, 0);
}

// A&S 7.1.26 erf approx: max abs err 1.5e-7; one v_exp + ~10 fma.
__device__ __forceinline__ float erf_approx(float x) {
    float ax = fabsf(x);
    float t  = 1.f/(1.f + 0.3275911f*ax);
    float y  = t*(0.254829592f + t*(-0.284496736f + t*(1.421413741f +
               t*(-1.453152027f + t*1.061405429f))));
    float r  = 1.f - y*__expf(-ax*ax);
    return x < 0.f ? -r : r;
}

// bf16 weight arena offsets in d_ws (elements)
constexpr int WOFF_QKV  = 0;        // 288*96
constexpr int WOFF_PROJ = 27648;    // 96*96
constexpr int WOFF_FC1  = 36864;    // 384*96
constexpr int WOFF_FC2  = 73728;    // 96*384
constexpr int WTOT      = 110592;

__global__ void prep_kernel(const float* __restrict__ qkv_w,
                            const float* __restrict__ proj_w,
                            const float* __restrict__ fc1w,
                            const float* __restrict__ fc2w,
                            bf16* __restrict__ wsb) {
    int i = blockIdx.x*256 + threadIdx.x;
    if (i >= WTOT) return;
    float v;
    if      (i < WOFF_PROJ) v = qkv_w[i];
    else if (i < WOFF_FC1)  v = proj_w[i - WOFF_PROJ];
    else if (i < WOFF_FC2)  v = fc1w[i - WOFF_FC1];
    else                    v = fc2w[i - WOFF_FC2];
    wsb[i] = (bf16)v;
}

// ---- attention kernel LDS layout (bf16 elements, manual offsets) ----
constexpr int SQ_O  = 0;       // [4][64][32]  q (scaled, cols 24..31 zeroed)
constexpr int SK_O  = 8192;    // [4][64][24]  k (b-frag reads may spill -> x0 via zeroed q pad)
constexpr int SVT_O = 14336;   // [4][24][64]  v^T (junk cols d>=24 discarded)
constexpr int XO_O  = 20480;   // [64][104]    xln -> attn-out -> proj-out (padded stride)
constexpr int SP_O  = 27136;   // [64][64]     softmax P (bf16)
constexpr int SMEM_N= 31232;   // 62464 B

__global__ __launch_bounds__(256) void attn_kernel(
    const float* __restrict__ x,       // [B,C,H,W]
    const float* __restrict__ norm_w,
    const float* __restrict__ norm_b,
    const bf16*  __restrict__ wqkv,    // [288][96] bf16
    const float* __restrict__ qkv_b,
    const bf16*  __restrict__ wproj,   // [96][96] bf16
    const float* __restrict__ proj_b,
    const float* __restrict__ rpb,     // [225][4]
    float* __restrict__ hbuf)          // [B,C,H,W] = d_out (holds h)
{
    __shared__ __align__(16) bf16 sm[SMEM_N];
    const int tid  = threadIdx.x;
    const int wave = tid >> 6;
    const int lane = tid & 63;
    const int l16  = lane & 15;
    const int quad = lane >> 4;
    const int blk  = blockIdx.x;
    const int b    = blk >> 10;
    const int wid  = blk & (NWIN_-1);
    const int wh   = wid >> 5, ww = wid & (NWW_-1);

    // zero sQ pad (cols 24..31): one 16B store per (head,row); 256 rows = 1/thread
    { bf16x8 z = {}; *(bf16x8*)&sm[SQ_O + tid*32 + 24] = z; }

    // ---- Phase 1: roll-gather + LayerNorm -> xo (bf16) ----
    {
        const int t = tid >> 2, qa = tid & 3;
        const int i = t >> 3, j = t & 7;
        const int gh = (wh*WS_ + i + SHIFT_) & (H_-1);
        const int gw = (ww*WS_ + j + SHIFT_) & (W_-1);
        const float* xb = x + (size_t)b*C_*HW_ + gh*W_ + gw;
        float v[24]; float mu = 0.f, ss = 0.f;
        #pragma unroll
        for (int cc = 0; cc < 24; ++cc) {
            v[cc] = xb[(size_t)(qa*24+cc)*HW_];
            mu += v[cc]; ss += v[cc]*v[cc];
        }
        mu += __shfl_xor(mu,1); mu += __shfl_xor(mu,2);
        ss += __shfl_xor(ss,1); ss += __shfl_xor(ss,2);
        mu *= (1.f/C_);
        float rstd = rsqrtf(ss*(1.f/C_) - mu*mu + EPS_);
        #pragma unroll
        for (int cc = 0; cc < 24; ++cc) {
            int c = qa*24+cc;
            sm[XO_O + t*104 + c] = (bf16)((v[cc]-mu)*rstd*norm_w[c] + norm_b[c]);
        }
    }
    __syncthreads();

    // ---- Phase 2: QKV via MFMA (M=64, N=288, K=96) ----
    {
        bf16x8 af[4][3];
        #pragma unroll
        for (int mt = 0; mt < 4; ++mt)
            #pragma unroll
            for (int kk = 0; kk < 3; ++kk)
                af[mt][kk] = *(const bf16x8*)&sm[XO_O + (mt*16+l16)*104 + kk*32 + quad*8];
        for (int nt = wave; nt < 18; nt += 4) {
            const int col = nt*16 + l16;
            bf16x8 bw[3];
            #pragma unroll
            for (int kk = 0; kk < 3; ++kk)
                bw[kk] = *(const bf16x8*)(wqkv + (size_t)col*96 + kk*32 + quad*8);
            const float bias = qkv_b[col];
            const int which = col / 96;        // wave-uniform (96 = 6*16)
            const int rem = col % 96;
            const int hh = rem / 24, d = rem % 24;
            #pragma unroll
            for (int mt = 0; mt < 4; ++mt) {
                f32x4 acc = {};
                #pragma unroll
                for (int kk = 0; kk < 3; ++kk) acc = mfma16(af[mt][kk], bw[kk], acc);
                const int tb = mt*16 + quad*4;
                if (which == 0) {
                    #pragma unroll
                    for (int r = 0; r < 4; ++r)
                        sm[SQ_O + (hh*64 + tb + r)*32 + d] = (bf16)((acc[r] + bias)*SCALE_);
                } else if (which == 1) {
                    #pragma unroll
                    for (int r = 0; r < 4; ++r)
                        sm[SK_O + (hh*64 + tb + r)*24 + d] = (bf16)(acc[r] + bias);
                } else {
                    bf16x4 pv;
                    #pragma unroll
                    for (int r = 0; r < 4; ++r) pv[r] = (bf16)(acc[r] + bias);
                    *(bf16x4*)&sm[SVT_O + (hh*24 + d)*64 + tb] = pv; // 4 consecutive t
                }
            }
        }
    }
    __syncthreads();

    // ---- Phase 3: per-head scores + softmax + PV (wave w owns queries w*16..+15) ----
    const int qrow0 = wave*16;
    for (int h = 0; h < NH_; ++h) {
        bf16x8 aq = *(const bf16x8*)&sm[SQ_O + (h*64 + qrow0 + l16)*32 + quad*8];
        f32x4 accS[4];
        #pragma unroll
        for (int kt = 0; kt < 4; ++kt) {
            bf16x8 bk = *(const bf16x8*)&sm[SK_O + (h*64 + kt*16 + l16)*24 + quad*8];
            f32x4 z = {};
            accS[kt] = mfma16(aq, bk, z);
        }
        // bias + mask + softmax in C layout (col=key=kt*16+l16, row=qrow0+quad*4+r)
        float s[4][4];
        #pragma unroll
        for (int kt = 0; kt < 4; ++kt) {
            const int key = kt*16 + l16;
            const int ki = key >> 3, kj = key & 7;
            const int labk = (((wh*8+ki) >= H_-WS_) + ((wh*8+ki) >= H_-SHIFT_))*3
                           +  ((ww*8+kj) >= W_-WS_) + ((ww*8+kj) >= W_-SHIFT_);
            #pragma unroll
            for (int r = 0; r < 4; ++r) {
                const int q = qrow0 + quad*4 + r;
                const int ti = q >> 3, tj = q & 7;
                const int labq = (((wh*8+ti) >= H_-WS_) + ((wh*8+ti) >= H_-SHIFT_))*3
                               +  ((ww*8+tj) >= W_-WS_) + ((ww*8+tj) >= W_-SHIFT_);
                const int ridx = (ti - ki + 7)*15 + (tj - kj + 7);
                float val = accS[kt][r] + rpb[ridx*NH_ + h];
                if (labk != labq) val -= 100.f;
                s[kt][r] = val;
            }
        }
        #pragma unroll
        for (int r = 0; r < 4; ++r) {
            float m = fmaxf(fmaxf(s[0][r], s[1][r]), fmaxf(s[2][r], s[3][r]));
            m = fmaxf(m, __shfl_xor(m,1)); m = fmaxf(m, __shfl_xor(m,2));
            m = fmaxf(m, __shfl_xor(m,4)); m = fmaxf(m, __shfl_xor(m,8));
            float su = 0.f;
            #pragma unroll
            for (int kt = 0; kt < 4; ++kt) { s[kt][r] = __expf(s[kt][r]-m); su += s[kt][r]; }
            su += __shfl_xor(su,1); su += __shfl_xor(su,2);
            su += __shfl_xor(su,4); su += __shfl_xor(su,8);
            const float inv = 1.f/su;
            #pragma unroll
            for (int kt = 0; kt < 4; ++kt)
                sm[SP_O + (qrow0 + quad*4 + r)*64 + kt*16 + l16] = (bf16)(s[kt][r]*inv);
        }
        __syncthreads();  // safety: P write -> P read (wave-local rows, but cheap insurance)

        // PV: O[q][d] = P @ V  (K=64 keys, 2 k-steps; N=24 dims in 2 tiles)
        bf16x8 ap0 = *(const bf16x8*)&sm[SP_O + (qrow0 + l16)*64 + quad*8];
        bf16x8 ap1 = *(const bf16x8*)&sm[SP_O + (qrow0 + l16)*64 + 32 + quad*8];
        #pragma unroll
        for (int nt2 = 0; nt2 < 2; ++nt2) {
            const int d = nt2*16 + l16;
            bf16x8 bv0 = *(const bf16x8*)&sm[SVT_O + (h*24 + d)*64 + quad*8];
            bf16x8 bv1 = *(const bf16x8*)&sm[SVT_O + (h*24 + d)*64 + 32 + quad*8];
            f32x4 acc = {};
            acc = mfma16(ap0, bv0, acc);
            acc = mfma16(ap1, bv1, acc);
            if (d < HD_) {
                #pragma unroll
                for (int r = 0; r < 4; ++r)
                    sm[XO_O + (qrow0 + quad*4 + r)*104 + h*24 + d] = (bf16)acc[r];
            }
        }
    }

    // ---- Phase 4: proj (wave-local rows), then coalesced residual writeout ----
    {
        bf16x8 ao[3];
        #pragma unroll
        for (int kk = 0; kk < 3; ++kk)
            ao[kk] = *(const bf16x8*)&sm[XO_O + (qrow0 + l16)*104 + kk*32 + quad*8];
        for (int nt = 0; nt < 6; ++nt) {
            const int oc = nt*16 + l16;
            bf16x8 bw[3];
            #pragma unroll
            for (int kk = 0; kk < 3; ++kk)
                bw[kk] = *(const bf16x8*)(wproj + (size_t)oc*96 + kk*32 + quad*8);
            f32x4 acc = {};
            #pragma unroll
            for (int kk = 0; kk < 3; ++kk) acc = mfma16(ao[kk], bw[kk], acc);
            #pragma unroll
            for (int r = 0; r < 4; ++r)
                sm[XO_O + (qrow0 + quad*4 + r)*104 + oc] = (bf16)acc[r];
        }
    }
    __syncthreads();
    for (int idx = tid; idx < NT_*C_; idx += 256) {
        const int t = idx & 63, o = idx >> 6;
        const int i = t >> 3, j = t & 7;
        const int gh = (wh*WS_ + i + SHIFT_) & (H_-1);
        const int gw = (ww*WS_ + j + SHIFT_) & (W_-1);
        const size_t g = (size_t)(b*C_ + o)*HW_ + gh*W_ + gw;
        hbuf[g] = x[g] + (float)sm[XO_O + t*104 + o] + proj_b[o];
    }
}

// ---- MLP kernel LDS layout ----
constexpr int Y_O   = 0;      // [64][104] bf16: y (LN2) then fc2-out
constexpr int G_O   = 6656;   // [64][392] bf16: gelu(fc1); first 24832B doubles as f32 h-stage
constexpr int MSM_N = 31744;  // 63488 B

__global__ __launch_bounds__(256) void mlp_kernel(
    const float* __restrict__ n2w, const float* __restrict__ n2b,
    const bf16*  __restrict__ wfc1, const float* __restrict__ fc1b,
    const bf16*  __restrict__ wfc2, const float* __restrict__ fc2b,
    float* __restrict__ out)   // [B,C,H,W], holds h on entry; updated in place
{
    __shared__ __align__(16) bf16 sm[MSM_N];
    float* sh = (float*)&sm[G_O];          // [64][97] f32 staging
    const int tid = threadIdx.x;
    const int wave = tid >> 6, lane = tid & 63, l16 = lane & 15, quad = lane >> 4;
    const int tok0 = blockIdx.x*64;
    const int b  = tok0 >> 16;             // / HW
    const int r0 = tok0 & (HW_-1);
    float* hbase = out + (size_t)b*C_*HW_ + r0;

    // coalesced h stage
    for (int idx = tid; idx < 6144; idx += 256) {
        int c = idx >> 6, t = idx & 63;
        sh[t*97 + c] = hbase[(size_t)c*HW_ + t];
    }
    __syncthreads();
    // LN2 -> y bf16
    {
        const int t = tid >> 2, qa = tid & 3;
        float v[24]; float mu = 0.f, ss = 0.f;
        #pragma unroll
        for (int cc = 0; cc < 24; ++cc) {
            v[cc] = sh[t*97 + qa*24 + cc];
            mu += v[cc]; ss += v[cc]*v[cc];
        }
        mu += __shfl_xor(mu,1); mu += __shfl_xor(mu,2);
        ss += __shfl_xor(ss,1); ss += __shfl_xor(ss,2);
        mu *= (1.f/C_);
        float rstd = rsqrtf(ss*(1.f/C_) - mu*mu + EPS_);
        #pragma unroll
        for (int cc = 0; cc < 24; ++cc) {
            int c = qa*24+cc;
            sm[Y_O + t*104 + c] = (bf16)((v[cc]-mu)*rstd*n2w[c] + n2b[c]);
        }
    }
    __syncthreads();
    // fc1 + GELU -> G  (M=64, N=384, K=96)
    {
        bf16x8 af[4][3];
        #pragma unroll
        for (int mt = 0; mt < 4; ++mt)
            #pragma unroll
            for (int kk = 0; kk < 3; ++kk)
                af[mt][kk] = *(const bf16x8*)&sm[Y_O + (mt*16+l16)*104 + kk*32 + quad*8];
        for (int nt = wave; nt < 24; nt += 4) {
            const int u = nt*16 + l16;
            bf16x8 bw[3];
            #pragma unroll
            for (int kk = 0; kk < 3; ++kk)
                bw[kk] = *(const bf16x8*)(wfc1 + (size_t)u*96 + kk*32 + quad*8);
            const float bias = fc1b[u];
            #pragma unroll
            for (int mt = 0; mt < 4; ++mt) {
                f32x4 acc = {};
                #pragma unroll
                for (int kk = 0; kk < 3; ++kk) acc = mfma16(af[mt][kk], bw[kk], acc);
                #pragma unroll
                for (int r = 0; r < 4; ++r) {
                    float tv = acc[r] + bias;
                    float g = 0.5f*tv*(1.f + erf_approx(tv*0.70710678118654752f));
                    sm[G_O + (mt*16 + quad*4 + r)*392 + u] = (bf16)g;
                }
            }
        }
    }
    __syncthreads();
    // fc2 (M=64, N=96, K=384); wave w owns M-tile w
    {
        bf16x8 ag[12];
        #pragma unroll
        for (int kk = 0; kk < 12; ++kk)
            ag[kk] = *(const bf16x8*)&sm[G_O + (wave*16+l16)*392 + kk*32 + quad*8];
        for (int nt = 0; nt < 6; ++nt) {
            const int c = nt*16 + l16;
            f32x4 acc = {};
            #pragma unroll
            for (int kk = 0; kk < 12; ++kk) {
                bf16x8 bw = *(const bf16x8*)(wfc2 + (size_t)c*384 + kk*32 + quad*8);
                acc = mfma16(ag[kk], bw, acc);
            }
            const float bias = fc2b[c];
            #pragma unroll
            for (int r = 0; r < 4; ++r)
                sm[Y_O + (wave*16 + quad*4 + r)*104 + c] = (bf16)(acc[r] + bias);
        }
    }
    __syncthreads();
    // residual + in-place store (coalesced)
    for (int idx = tid; idx < 6144; idx += 256) {
        int c = idx >> 6, t = idx & 63;
        size_t g = (size_t)c*HW_ + t;
        hbase[g] = hbase[g] + (float)sm[Y_O + t*104 + c];
    }
}

extern "C" void kernel_launch(void* const* d_in, const int* in_sizes, int n_in,
                              void* d_out, int out_size, void* d_ws, size_t ws_size,
                              hipStream_t stream) {
    const float* x      = (const float*)d_in[0];
    const float* norm_w = (const float*)d_in[1];
    const float* norm_b = (const float*)d_in[2];
    const float* qkv_w  = (const float*)d_in[3];
    const float* qkv_b  = (const float*)d_in[4];
    const float* proj_w = (const float*)d_in[5];
    const float* proj_b = (const float*)d_in[6];
    const float* rpb    = (const float*)d_in[7];
    const float* n2w    = (const float*)d_in[8];
    const float* n2b    = (const float*)d_in[9];
    const float* fc1w   = (const float*)d_in[10];
    const float* fc1b   = (const float*)d_in[11];
    const float* fc2w   = (const float*)d_in[12];
    const float* fc2b   = (const float*)d_in[13];

    float* outp = (float*)d_out;
    bf16*  wsb  = (bf16*)d_ws;   // 221 KB bf16 weight arena

    prep_kernel<<<(WTOT+255)/256, 256, 0, stream>>>(qkv_w, proj_w, fc1w, fc2w, wsb);
    attn_kernel<<<B_*NWIN_, 256, 0, stream>>>(x, norm_w, norm_b,
                                              wsb + WOFF_QKV, qkv_b,
                                              wsb + WOFF_PROJ, proj_b,
                                              rpb, outp);
    mlp_kernel<<<B_*HW_/64, 256, 0, stream>>>(n2w, n2b,
                                              wsb + WOFF_FC1, fc1b,
                                              wsb + WOFF_FC2, fc2b,
                                              outp);
}

// Round 4
// 539.032 us; speedup vs baseline: 20.4243x; 1.2604x over previous
//
#include <hip/hip_runtime.h>
#include <hip/hip_bf16.h>
#include <math.h>

// ---- problem constants ----
constexpr int B_    = 4;
constexpr int C_    = 96;
constexpr int H_    = 256;
constexpr int W_    = 256;
constexpr int WS_   = 8;
constexpr int NH_   = 4;
constexpr int SHIFT_= 4;
constexpr int HD_   = 24;
constexpr int NT_   = 64;
constexpr int NWW_  = 32;
constexpr int MLPH_ = 384;
constexpr int HW_   = H_*W_;
constexpr float EPS_   = 1e-6f;
constexpr float SCALE_ = 0.20412414523193150f; // 24^-0.5

using bf16   = __bf16;
using bf16x8 = __attribute__((ext_vector_type(8))) __bf16;
using bf16x4 = __attribute__((ext_vector_type(4))) __bf16;
using f32x4  = __attribute__((ext_vector_type(4))) float;

__device__ __forceinline__ f32x4 mfma16(bf16x8 a, bf16x8 b, f32x4 c) {
    return __builtin_amdgcn_mfma_f32_16x16x32_bf16(a, b, c, 0, 0, 0);
}

// A&S 7.1.26 erf approx: max abs err 1.5e-7
__device__ __forceinline__ float erf_approx(float x) {
    float ax = fabsf(x);
    float t  = 1.f/(1.f + 0.3275911f*ax);
    float y  = t*(0.254829592f + t*(-0.284496736f + t*(1.421413741f +
               t*(-1.453152027f + t*1.061405429f))));
    float r  = 1.f - y*__expf(-ax*ax);
    return x < 0.f ? -r : r;
}

// ---- workspace layout (bytes) ----
// xt/hbf : [B*HW][96] bf16 = 50,331,648 B  (x transposed; attn overwrites with h in place)
// weights: per-head-grouped qkv [320][96], proj [96][96], fc1 [384][96], fc2 [96][384] (bf16)
// bq2    : [320] f32 (per-head-grouped qkv bias, q-scale folded)
constexpr size_t XT_B    = (size_t)B_*HW_*96*2;           // 50331648
constexpr int    WQ2_E   = 320*96;                        // 30720
constexpr int    WPR_E   = 96*96;                         // 9216
constexpr int    WF1_E   = 384*96;                        // 36864
constexpr int    WF2_E   = 96*384;                        // 36864
constexpr int    WSUM_E  = WQ2_E + WPR_E + WF1_E + WF2_E; // 113664
constexpr int    NBQ     = 320;
constexpr int    WBLKS   = (WSUM_E + NBQ + 255)/256;      // 446
constexpr int    TBLKS   = B_*HW_/64;                     // 4096

__global__ __launch_bounds__(256) void prep_kernel(
    const float* __restrict__ x,
    const float* __restrict__ qkv_w, const float* __restrict__ qkv_b,
    const float* __restrict__ proj_w, const float* __restrict__ fc1w,
    const float* __restrict__ fc2w,
    bf16* __restrict__ xt, bf16* __restrict__ warena, float* __restrict__ bq2)
{
    __shared__ float st[64*97];
    const int tid = threadIdx.x;
    if (blockIdx.x < WBLKS) {
        int i = blockIdx.x*256 + tid;
        if (i < WQ2_E) {
            int R = i/96, c = i%96;
            int h = R/80, s = R%80;
            float v;
            if      (s < 24) v = qkv_w[(h*24+s)*96 + c] * SCALE_;
            else if (s < 48) v = qkv_w[(96 + h*24 + s-24)*96 + c];
            else if (s < 72) v = qkv_w[(192 + h*24 + s-48)*96 + c];
            else             v = 0.f;
            warena[i] = (bf16)v;
        } else if (i < WQ2_E + WPR_E) {
            warena[i] = (bf16)proj_w[i - WQ2_E];
        } else if (i < WQ2_E + WPR_E + WF1_E) {
            warena[i] = (bf16)fc1w[i - WQ2_E - WPR_E];
        } else if (i < WSUM_E) {
            warena[i] = (bf16)fc2w[i - WQ2_E - WPR_E - WF1_E];
        } else if (i < WSUM_E + NBQ) {
            int j = i - WSUM_E;
            int h = j/80, s = j%80;
            float v;
            if      (s < 24) v = qkv_b[h*24+s] * SCALE_;
            else if (s < 48) v = qkv_b[96 + h*24 + s-24];
            else if (s < 72) v = qkv_b[192 + h*24 + s-48];
            else             v = 0.f;
            bq2[j] = v;
        }
        return;
    }
    // ---- transpose branch: 64 consecutive pixels per block ----
    const int tb = blockIdx.x - WBLKS;
    const int b  = tb >> 10;
    const int r0 = (tb & 1023)*64;
    const float* xb = x + (size_t)(b*96)*HW_ + r0;
    for (int idx = tid; idx < 6144; idx += 256) {
        int c = idx >> 6, t = idx & 63;
        st[t*97 + c] = xb[(size_t)c*HW_ + t];
    }
    __syncthreads();
    {
        const int t = tid >> 2, qa = tid & 3;
        bf16* dst = xt + ((size_t)(b<<16) + r0 + t)*96 + qa*24;
        const float* sp_ = &st[t*97 + qa*24];
        #pragma unroll
        for (int k = 0; k < 3; ++k) {
            bf16x8 o;
            #pragma unroll
            for (int j = 0; j < 8; ++j) o[j] = (bf16)sp_[k*8 + j];
            *(bf16x8*)(dst + k*8) = o;
        }
    }
}

// ---- attention kernel LDS (bf16 el offsets) ----
constexpr int ASQ = 0;      // [64][40]  q (scale folded, cols 24..31 zeroed)
constexpr int ASK = 2560;   // [64][24]  k (b-frag tail spills into ASV: junk x 0)
constexpr int ASV = 4096;   // [24][72]  v^T
constexpr int ASP = 5824;   // [64][72]  softmax P
constexpr int AXO = 10432;  // [64][104] xln -> attn-out -> proj-out
constexpr int ASM_N = 17088; // 34176 B

__global__ __launch_bounds__(256) void attn_kernel(
    bf16* __restrict__ xt,             // [B*HW][96] x (bf16); overwritten with h
    const float* __restrict__ norm_w, const float* __restrict__ norm_b,
    const bf16*  __restrict__ wq2,     // [320][96] per-head q|k|v|pad
    const float* __restrict__ bq2,     // [320]
    const bf16*  __restrict__ wproj,   // [96][96]
    const float* __restrict__ proj_b,
    const float* __restrict__ rpb)     // [225][4] f32
{
    __shared__ __align__(16) bf16 sm[ASM_N];
    const int tid  = threadIdx.x;
    const int wave = tid >> 6, lane = tid & 63;
    const int l16  = lane & 15, quad = lane >> 4;
    const int blk  = blockIdx.x;
    const int b    = blk >> 10;
    const int wid  = blk & 1023;
    const int wh   = wid >> 5, ww = wid & 31;

    // zero Q pad cols 24..31 (once; later stores touch cols <24 only)
    if (tid < 64) { bf16x8 z = {}; *(bf16x8*)&sm[ASQ + tid*40 + 24] = z; }

    // ---- Phase 1: gather NHWC tokens + LayerNorm -> AXO ----
    const int t  = tid >> 2, qa = tid & 3;
    const int wi = t >> 3, wj = t & 7;
    const int gh = (wh*WS_ + wi + SHIFT_) & (H_-1);
    const int gw = (ww*WS_ + wj + SHIFT_) & (W_-1);
    const size_t pix = (size_t)(b<<16) + gh*W_ + gw;
    {
        const bf16* xp = xt + pix*96 + qa*24;
        float v[24]; float mu = 0.f, ss = 0.f;
        #pragma unroll
        for (int k = 0; k < 3; ++k) {
            bf16x8 h8 = ((const bf16x8*)xp)[k];
            #pragma unroll
            for (int j = 0; j < 8; ++j) {
                v[k*8+j] = (float)h8[j];
                mu += v[k*8+j]; ss += v[k*8+j]*v[k*8+j];
            }
        }
        mu += __shfl_xor(mu,1); mu += __shfl_xor(mu,2);
        ss += __shfl_xor(ss,1); ss += __shfl_xor(ss,2);
        mu *= (1.f/C_);
        float rstd = rsqrtf(ss*(1.f/C_) - mu*mu + EPS_);
        #pragma unroll
        for (int cc = 0; cc < 24; ++cc) {
            int c = qa*24 + cc;
            sm[AXO + t*104 + c] = (bf16)((v[cc]-mu)*rstd*norm_w[c] + norm_b[c]);
        }
    }
    __syncthreads();

    // A-frags of LN'd x, kept in registers for all heads
    bf16x8 af[4][3];
    #pragma unroll
    for (int mt = 0; mt < 4; ++mt)
        #pragma unroll
        for (int kk = 0; kk < 3; ++kk)
            af[mt][kk] = *(const bf16x8*)&sm[AXO + (mt*16+l16)*104 + kk*32 + quad*8];

    const int qrow0 = wave*16;
    for (int h = 0; h < NH_; ++h) {
        // ---- per-head QKV: 5 N-tiles (80 cols: q24|k24|v24|pad8) over 4 waves ----
        for (int jt = 0; jt < 5; ++jt) {
            if (((h*5 + jt) & 3) != wave) continue;
            const int s   = jt*16 + l16;           // 0..79 within head
            const int row = h*80 + s;
            bf16x8 bw[3];
            #pragma unroll
            for (int kk = 0; kk < 3; ++kk)
                bw[kk] = *(const bf16x8*)(wq2 + (size_t)row*96 + kk*32 + quad*8);
            const float bias = bq2[row];
            #pragma unroll
            for (int mt = 0; mt < 4; ++mt) {
                f32x4 acc = {};
                #pragma unroll
                for (int kk = 0; kk < 3; ++kk) acc = mfma16(af[mt][kk], bw[kk], acc);
                const int tb = mt*16 + quad*4;
                if (s < 24) {
                    #pragma unroll
                    for (int r = 0; r < 4; ++r)
                        sm[ASQ + (tb+r)*40 + s] = (bf16)(acc[r] + bias);
                } else if (s < 48) {
                    #pragma unroll
                    for (int r = 0; r < 4; ++r)
                        sm[ASK + (tb+r)*24 + (s-24)] = (bf16)(acc[r] + bias);
                } else if (s < 72) {
                    bf16x4 pv;
                    #pragma unroll
                    for (int r = 0; r < 4; ++r) pv[r] = (bf16)(acc[r] + bias);
                    *(bf16x4*)&sm[ASV + (s-48)*72 + tb] = pv;
                }
            }
        }
        __syncthreads();

        // ---- scores + softmax (wave owns queries qrow0..+15) ----
        bf16x8 aq = *(const bf16x8*)&sm[ASQ + (qrow0 + l16)*40 + quad*8];
        f32x4 accS[4];
        #pragma unroll
        for (int kt = 0; kt < 4; ++kt) {
            bf16x8 bk = *(const bf16x8*)&sm[ASK + (kt*16+l16)*24 + quad*8];
            f32x4 z = {};
            accS[kt] = mfma16(aq, bk, z);
        }
        float s_[4][4];
        #pragma unroll
        for (int kt = 0; kt < 4; ++kt) {
            const int key = kt*16 + l16;
            const int ki = key >> 3, kj = key & 7;
            const int labk = (((wh*8+ki) >= H_-WS_) + ((wh*8+ki) >= H_-SHIFT_))*3
                           +  ((ww*8+kj) >= W_-WS_) + ((ww*8+kj) >= W_-SHIFT_);
            #pragma unroll
            for (int r = 0; r < 4; ++r) {
                const int q = qrow0 + quad*4 + r;
                const int ti = q >> 3, tj = q & 7;
                const int labq = (((wh*8+ti) >= H_-WS_) + ((wh*8+ti) >= H_-SHIFT_))*3
                               +  ((ww*8+tj) >= W_-WS_) + ((ww*8+tj) >= W_-SHIFT_);
                const int ridx = (ti - ki + 7)*15 + (tj - kj + 7);
                float val = accS[kt][r] + rpb[ridx*NH_ + h];
                if (labk != labq) val -= 100.f;
                s_[kt][r] = val;
            }
        }
        #pragma unroll
        for (int r = 0; r < 4; ++r) {
            float m = fmaxf(fmaxf(s_[0][r], s_[1][r]), fmaxf(s_[2][r], s_[3][r]));
            m = fmaxf(m, __shfl_xor(m,1)); m = fmaxf(m, __shfl_xor(m,2));
            m = fmaxf(m, __shfl_xor(m,4)); m = fmaxf(m, __shfl_xor(m,8));
            float su = 0.f;
            #pragma unroll
            for (int kt = 0; kt < 4; ++kt) { s_[kt][r] = __expf(s_[kt][r]-m); su += s_[kt][r]; }
            su += __shfl_xor(su,1); su += __shfl_xor(su,2);
            su += __shfl_xor(su,4); su += __shfl_xor(su,8);
            const float inv = 1.f/su;
            #pragma unroll
            for (int kt = 0; kt < 4; ++kt)
                sm[ASP + (qrow0 + quad*4 + r)*72 + kt*16 + l16] = (bf16)(s_[kt][r]*inv);
        }
        __syncthreads();

        // ---- PV -> attn-out cols h*24..+23 of AXO ----
        bf16x8 ap0 = *(const bf16x8*)&sm[ASP + (qrow0+l16)*72 + quad*8];
        bf16x8 ap1 = *(const bf16x8*)&sm[ASP + (qrow0+l16)*72 + 32 + quad*8];
        #pragma unroll
        for (int nt2 = 0; nt2 < 2; ++nt2) {
            const int d = nt2*16 + l16;
            bf16x8 bv0 = *(const bf16x8*)&sm[ASV + d*72 + quad*8];
            bf16x8 bv1 = *(const bf16x8*)&sm[ASV + d*72 + 32 + quad*8];
            f32x4 acc = {};
            acc = mfma16(ap0, bv0, acc);
            acc = mfma16(ap1, bv1, acc);
            if (d < HD_) {
                #pragma unroll
                for (int r = 0; r < 4; ++r)
                    sm[AXO + (qrow0 + quad*4 + r)*104 + h*24 + d] = (bf16)acc[r];
            }
        }
        __syncthreads();   // protect sq/sk/sv/sp before next head's QKV stores
    }

    // ---- proj (wave-local rows) ----
    {
        bf16x8 ao[3];
        #pragma unroll
        for (int kk = 0; kk < 3; ++kk)
            ao[kk] = *(const bf16x8*)&sm[AXO + (qrow0 + l16)*104 + kk*32 + quad*8];
        for (int nt = 0; nt < 6; ++nt) {
            const int oc = nt*16 + l16;
            bf16x8 bw[3];
            #pragma unroll
            for (int kk = 0; kk < 3; ++kk)
                bw[kk] = *(const bf16x8*)(wproj + (size_t)oc*96 + kk*32 + quad*8);
            f32x4 acc = {};
            #pragma unroll
            for (int kk = 0; kk < 3; ++kk) acc = mfma16(ao[kk], bw[kk], acc);
            #pragma unroll
            for (int r = 0; r < 4; ++r)
                sm[AXO + (qrow0 + quad*4 + r)*104 + oc] = (bf16)acc[r];
        }
    }
    __syncthreads();

    // ---- residual + write h back into xt (in place; tokens are block-exclusive) ----
    {
        bf16* xp = xt + pix*96 + qa*24;
        #pragma unroll
        for (int k = 0; k < 3; ++k) {
            bf16x8 xv = ((const bf16x8*)xp)[k];
            bf16x8 xo = *(const bf16x8*)&sm[AXO + t*104 + qa*24 + k*8];
            bf16x8 o;
            #pragma unroll
            for (int j = 0; j < 8; ++j)
                o[j] = (bf16)((float)xv[j] + (float)xo[j] + proj_b[qa*24 + k*8 + j]);
            *(bf16x8*)(xp + k*8) = o;
        }
    }
}

// ---- MLP kernel LDS (bf16 el offsets) ----
constexpr int MY  = 0;       // [64][104] y (LN2)
constexpr int MH  = 6656;    // [64][104] h (bf16 copy for residual)
constexpr int MR  = 13312;   // G [64][136] bf16  OR  stage [64][97] f32 (12416 el)
constexpr int MSM = 25728;   // 51456 B

__global__ __launch_bounds__(256) void mlp_kernel(
    const bf16*  __restrict__ hbf,    // [B*HW][96] h (== xt buffer)
    const float* __restrict__ n2w, const float* __restrict__ n2b,
    const bf16*  __restrict__ wfc1, const float* __restrict__ fc1b,
    const bf16*  __restrict__ wfc2, const float* __restrict__ fc2b,
    float* __restrict__ out)          // [B,C,H,W] f32
{
    __shared__ __align__(16) bf16 sm[MSM];
    float* stage = (float*)&sm[MR];
    const int tid  = threadIdx.x;
    const int wave = tid >> 6, lane = tid & 63;
    const int l16  = lane & 15, quad = lane >> 4;
    const int pb = blockIdx.x;
    const int b  = pb >> 10;
    const int r0 = (pb & 1023)*64;

    // ---- Phase 0: load h (coalesced), stash bf16 copy, LN2 -> MY ----
    {
        const int t = tid >> 2, qa = tid & 3;
        const bf16* hp = hbf + ((size_t)(b<<16) + r0 + t)*96 + qa*24;
        bf16x8 h8[3]; float v[24]; float mu = 0.f, ss = 0.f;
        #pragma unroll
        for (int k = 0; k < 3; ++k) {
            h8[k] = ((const bf16x8*)hp)[k];
            *(bf16x8*)&sm[MH + t*104 + qa*24 + k*8] = h8[k];
            #pragma unroll
            for (int j = 0; j < 8; ++j) {
                v[k*8+j] = (float)h8[k][j];
                mu += v[k*8+j]; ss += v[k*8+j]*v[k*8+j];
            }
        }
        mu += __shfl_xor(mu,1); mu += __shfl_xor(mu,2);
        ss += __shfl_xor(ss,1); ss += __shfl_xor(ss,2);
        mu *= (1.f/C_);
        float rstd = rsqrtf(ss*(1.f/C_) - mu*mu + EPS_);
        #pragma unroll
        for (int cc = 0; cc < 24; ++cc) {
            int c = qa*24 + cc;
            sm[MY + t*104 + c] = (bf16)((v[cc]-mu)*rstd*n2w[c] + n2b[c]);
        }
    }
    __syncthreads();

    bf16x8 af[4][3];
    #pragma unroll
    for (int mt = 0; mt < 4; ++mt)
        #pragma unroll
        for (int kk = 0; kk < 3; ++kk)
            af[mt][kk] = *(const bf16x8*)&sm[MY + (mt*16+l16)*104 + kk*32 + quad*8];

    f32x4 acc2[6];
    #pragma unroll
    for (int n = 0; n < 6; ++n) acc2[n] = (f32x4){};

    // ---- 3 chunks of 128 hidden units: fc1+GELU -> G, then fc2 partial ----
    for (int ci = 0; ci < 3; ++ci) {
        #pragma unroll
        for (int rep = 0; rep < 2; ++rep) {
            const int nt = wave + rep*4;
            const int ul = nt*16 + l16;        // 0..127 in chunk
            const int u  = ci*128 + ul;
            bf16x8 bw[3];
            #pragma unroll
            for (int kk = 0; kk < 3; ++kk)
                bw[kk] = *(const bf16x8*)(wfc1 + (size_t)u*96 + kk*32 + quad*8);
            const float bias = fc1b[u];
            #pragma unroll
            for (int mt = 0; mt < 4; ++mt) {
                f32x4 acc = {};
                #pragma unroll
                for (int kk = 0; kk < 3; ++kk) acc = mfma16(af[mt][kk], bw[kk], acc);
                #pragma unroll
                for (int r = 0; r < 4; ++r) {
                    float tv = acc[r] + bias;
                    float g  = 0.5f*tv*(1.f + erf_approx(tv*0.70710678118654752f));
                    sm[MR + (mt*16 + quad*4 + r)*136 + ul] = (bf16)g;
                }
            }
        }
        __syncthreads();
        bf16x8 ag[4];
        #pragma unroll
        for (int kq = 0; kq < 4; ++kq)
            ag[kq] = *(const bf16x8*)&sm[MR + (wave*16+l16)*136 + kq*32 + quad*8];
        #pragma unroll
        for (int nt2 = 0; nt2 < 6; ++nt2) {
            const int c = nt2*16 + l16;
            #pragma unroll
            for (int kq = 0; kq < 4; ++kq) {
                bf16x8 bw = *(const bf16x8*)(wfc2 + (size_t)c*384 + ci*128 + kq*32 + quad*8);
                acc2[nt2] = mfma16(ag[kq], bw, acc2[nt2]);
            }
        }
        __syncthreads();   // G reused next chunk; also guards stage overwrite below
    }

    // ---- residual sum into f32 stage (overlaps dead G region) ----
    #pragma unroll
    for (int nt2 = 0; nt2 < 6; ++nt2) {
        const int c = nt2*16 + l16;
        const float bias = fc2b[c];
        #pragma unroll
        for (int r = 0; r < 4; ++r) {
            const int row = wave*16 + quad*4 + r;
            stage[row*97 + c] = acc2[nt2][r] + bias + (float)sm[MH + row*104 + c];
        }
    }
    __syncthreads();

    // ---- coalesced NCHW f32 writeout ----
    float* ob = out + (size_t)(b*96)*HW_ + r0;
    for (int idx = tid; idx < 6144; idx += 256) {
        int c = idx >> 6, tt = idx & 63;
        ob[(size_t)c*HW_ + tt] = stage[tt*97 + c];
    }
}

extern "C" void kernel_launch(void* const* d_in, const int* in_sizes, int n_in,
                              void* d_out, int out_size, void* d_ws, size_t ws_size,
                              hipStream_t stream) {
    const float* x      = (const float*)d_in[0];
    const float* norm_w = (const float*)d_in[1];
    const float* norm_b = (const float*)d_in[2];
    const float* qkv_w  = (const float*)d_in[3];
    const float* qkv_b  = (const float*)d_in[4];
    const float* proj_w = (const float*)d_in[5];
    const float* proj_b = (const float*)d_in[6];
    const float* rpb    = (const float*)d_in[7];
    const float* n2w    = (const float*)d_in[8];
    const float* n2b    = (const float*)d_in[9];
    const float* fc1w   = (const float*)d_in[10];
    const float* fc1b   = (const float*)d_in[11];
    const float* fc2w   = (const float*)d_in[12];
    const float* fc2b   = (const float*)d_in[13];

    float* outp = (float*)d_out;
    char*  ws   = (char*)d_ws;
    bf16*  xt   = (bf16*)ws;                       // 50,331,648 B (x -> h in place)
    bf16*  wa   = (bf16*)(ws + XT_B);              // weight arena
    float* bq2  = (float*)(ws + XT_B + (size_t)WSUM_E*2);

    prep_kernel<<<WBLKS + TBLKS, 256, 0, stream>>>(x, qkv_w, qkv_b, proj_w,
                                                   fc1w, fc2w, xt, wa, bq2);
    attn_kernel<<<B_*1024, 256, 0, stream>>>(xt, norm_w, norm_b,
                                             wa, bq2,
                                             wa + WQ2_E, proj_b, rpb);
    mlp_kernel<<<TBLKS, 256, 0, stream>>>(xt, n2w, n2b,
                                          wa + WQ2_E + WPR_E, fc1b,
                                          wa + WQ2_E + WPR_E + WF1_E, fc2b,
                                          outp);
}